// Round 10
// baseline (111.858 us; speedup 1.0000x reference)
//
#include <hip/hip_runtime.h>
#include <hip/hip_bf16.h>

typedef short bf16x8 __attribute__((ext_vector_type(8)));
typedef short bf16x4 __attribute__((ext_vector_type(4)));
typedef float f32x4 __attribute__((ext_vector_type(4)));

#define TPB 512

// HW bf16 convert (RNE) — compiler emits v_cvt_pk_bf16_f32; do NOT hand-roll (r7/r8 lesson).
__device__ __forceinline__ unsigned short f2bf(float f) {
  __hip_bfloat16 h = __float2bfloat16(f);
  return __builtin_bit_cast(unsigned short, h);
}

__device__ __forceinline__ bf16x4 pack4(float a, float b, float c, float d) {
  bf16x4 v;
  v[0] = (short)f2bf(a); v[1] = (short)f2bf(b);
  v[2] = (short)f2bf(c); v[3] = (short)f2bf(d);
  return v;
}

// K=16 bf16 MFMA (A/B = 4 bf16 in 2 VGPRs). Fragment k-pattern = 4*(lane>>4)+j,
// which exactly matches the D-layout row pattern of the swapped QK^T output —
// so P feeds PV straight from registers, no LDS round-trip, no shuffles.
__device__ __forceinline__ f32x4 mfma16(bf16x4 a, bf16x4 b, f32x4 c) {
#if __has_builtin(__builtin_amdgcn_mfma_f32_16x16x16_bf16)
  return __builtin_amdgcn_mfma_f32_16x16x16_bf16(a, b, c, 0, 0, 0);
#elif __has_builtin(__builtin_amdgcn_mfma_f32_16x16x16bf16_1k)
  return __builtin_amdgcn_mfma_f32_16x16x16bf16_1k(a, b, c, 0, 0, 0);
#else
  f32x4 d;
  asm("v_mfma_f32_16x16x16_bf16 %0, %1, %2, %3" : "=v"(d) : "v"(a), "v"(b), "v"(c));
  return d;
#endif
}

// LDS map (ushort element units) — overlaid lifetimes (usable LDS/CU = 128 KiB, r3-r7 fit):
//   [0..8192)      sWin [64][128] swizzled          (staging -> af regs)
//   [0..20480)     Q [4][64][40] + K [4][64][40]    (phase 1 -> ak/bq regs)  overlays sWin
//   [0..8192)      ATT [64][128] swizzled           (PV out -> proj)         overlays Q
//   [20480..29696) VT [4][32][72]                   (phase 1 -> bv regs)
#define Q_OFF   0
#define K_OFF   10240
#define ATT_OFF 0
#define VT_OFF  20480
#define SMEM_ELEMS 29696 // 59,392 B -> 2 blocks/CU (118,784 <= 131,072)

__global__ void prep_weights(const float* __restrict__ wqkv,
                             const float* __restrict__ wproj,
                             unsigned short* __restrict__ wt) {
  int idx = blockIdx.x * 256 + threadIdx.x;
  if (idx < 384 * 128) {                 // wqkvT[n][k] = bf16(wqkv[k][n])
    int n = idx >> 7, k = idx & 127;
    wt[idx] = f2bf(wqkv[k * 384 + n]);
  } else if (idx < 384 * 128 + 128 * 128) { // wprojT[c][k] = bf16(wproj[k][c])
    int j = idx - 384 * 128;
    int c = j >> 7, k = j & 127;
    wt[idx] = f2bf(wproj[k * 128 + c]);
  }
}

// (TPB,2): VGPR cap 128 (empirical cap ~= 256/arg; r6: arg6->40 spilled, r7: arg4->64 tight).
// LDS pins residency at 2 blocks/CU = 16 waves/CU, which tolerates VGPR <= 128 (m69).
__launch_bounds__(TPB, 2)
__global__ void win_attn(const float* __restrict__ x,
                         const float* __restrict__ bqkv,
                         const float* __restrict__ bproj,
                         const unsigned short* __restrict__ wt,
                         float* __restrict__ out) {
  __shared__ __align__(16) unsigned short smem[SMEM_ELEMS];
  const int tid  = threadIdx.x;
  const int wave = tid >> 6;
  const int lane = tid & 63;
  const int g    = lane >> 4;   // 16-lane group id (0..3)
  const int l15  = lane & 15;

  const int wid = blockIdx.x;
  const int b = wid >> 8, wh = (wid >> 4) & 15, ww = wid & 15;
  const size_t winbase = (((size_t)b * 112 + wh * 7) * 112 + ww * 7) * 128;

  const unsigned short* wqkvT  = wt;               // [384][128] bf16
  const unsigned short* wprojT = wt + 384 * 128;   // [128][128] bf16

  const float scale = 0.17677669529663687f; // 1/sqrt(32)

  // ---------- stage window (fp32 -> bf16) -> sWin [64][128], XOR-swizzled ----------
  for (int q = tid; q < 2048; q += TPB) {
    int row = q >> 5, c4 = q & 31;
    ushort4 v4 = {0, 0, 0, 0};
    if (row < 49) {
      const float4* src = (const float4*)(x + winbase + ((row / 7) * 112 + (row % 7)) * 128);
      float4 f = src[c4];
      v4.x = f2bf(f.x); v4.y = f2bf(f.y); v4.z = f2bf(f.z); v4.w = f2bf(f.w);
    }
    int dst = row * 128 + ((c4 * 4) ^ ((row & 7) << 3));
    *(ushort4*)(&smem[dst]) = v4;
  }
  __syncthreads();   // bar1

  // ---------- phase 1: QKV = win @ w_qkv + b_qkv ----------
  bf16x8 af[4][4];
#pragma unroll
  for (int mt = 0; mt < 4; mt++)
#pragma unroll
    for (int kt = 0; kt < 4; kt++) {
      int row = mt * 16 + l15;
      int colE = kt * 32 + g * 8;
      af[mt][kt] = *(const bf16x8*)(&smem[row * 128 + (colE ^ ((row & 7) << 3))]);
    }
  __syncthreads();   // bar2: af in regs; Q/K/VT may now be written

  const f32x4 zero4 = {0.f, 0.f, 0.f, 0.f};

#pragma unroll
  for (int i = 0; i < 3; i++) {
    int nt = wave * 3 + i;          // 0..23 (n-tile of 384)
    int n  = nt * 16 + l15;         // output column
    float bias = bqkv[n];

    bf16x8 bw[4];
#pragma unroll
    for (int kt = 0; kt < 4; kt++)
      bw[kt] = *(const bf16x8*)(wqkvT + n * 128 + kt * 32 + g * 8);

    f32x4 acc[4] = {zero4, zero4, zero4, zero4};
#pragma unroll
    for (int kt = 0; kt < 4; kt++)
#pragma unroll
      for (int mt = 0; mt < 4; mt++)
        acc[mt] = __builtin_amdgcn_mfma_f32_16x16x32_bf16(af[mt][kt], bw[kt], acc[mt], 0, 0, 0);

    int sec = nt >> 3;       // 0=Q 1=K 2=V  (uniform per (wave,i))
    int hn  = n & 127;
    int h   = hn >> 5;
    int d   = hn & 31;
    if (sec == 2) {
      // V^T: 4 consecutive toks per mt -> packed ds_write_b64
#pragma unroll
      for (int mt = 0; mt < 4; mt++) {
        int tok0 = mt * 16 + g * 4;
        ushort4 pv;
        pv.x = f2bf(acc[mt][0] + bias);
        pv.y = f2bf(acc[mt][1] + bias);
        pv.z = f2bf(acc[mt][2] + bias);
        pv.w = f2bf(acc[mt][3] + bias);
        *(ushort4*)(&smem[VT_OFF + h * 2304 + d * 72 + tok0]) = pv;
      }
    } else {
      // Q gets the softmax 1/sqrt(d) scale folded into its store (saves VALU in phase 2)
      const int base = (sec == 0 ? Q_OFF : K_OFF) + h * 2560 + d;
      const float mul = (sec == 0) ? scale : 1.0f;
#pragma unroll
      for (int mt = 0; mt < 4; mt++)
#pragma unroll
        for (int r = 0; r < 4; r++) {
          int tok = mt * 16 + g * 4 + r;        // D row = 4*g + r  (m89-verified)
          smem[base + tok * 40] = f2bf((acc[mt][r] + bias) * mul);
        }
    }
  }
  __syncthreads();   // bar3: Q/K/VT complete

  // ---------- phase 2: attention, swapped QK^T (wave-pair per head) ----------
  // s = mfma(K, Q): D col = q-token (l15), row-regs = k-token (kt*16 + 4g + r).
  // Each l15 lane-quad (g=0..3) holds a full 64-k row of one q -> 2-shuffle softmax,
  // and the reg k-pattern (4 per g) IS the K=16 MFMA A-fragment pattern -> PV in-reg.
  const int h    = wave >> 1;
  const int half = wave & 1;        // query rows 0..31 or 32..63

  bf16x8 ak[4];
#pragma unroll
  for (int kt = 0; kt < 4; kt++) {
    int row = kt * 16 + l15;
    ak[kt] = *(const bf16x8*)(&smem[K_OFF + h * 2560 + row * 40 + g * 8]);
  }
  bf16x8 bq[2];
#pragma unroll
  for (int qt = 0; qt < 2; qt++) {
    int row = half * 32 + qt * 16 + l15;
    bq[qt] = *(const bf16x8*)(&smem[Q_OFF + h * 2560 + row * 40 + g * 8]);
  }
  // V B-fragments for K=16 PV: B[k=4g+j][col=d=l15] = VT[d][tok=kt*16+4g+j]
  bf16x4 bv16[2][4];
#pragma unroll
  for (int nt2 = 0; nt2 < 2; nt2++)
#pragma unroll
    for (int kt = 0; kt < 4; kt++)
      bv16[nt2][kt] = *(const bf16x4*)(&smem[VT_OFF + h * 2304 + (nt2 * 16 + l15) * 72 + kt * 16 + g * 4]);

  f32x4 s[4][2];
#pragma unroll
  for (int kt = 0; kt < 4; kt++)
#pragma unroll
    for (int qt = 0; qt < 2; qt++)
      s[kt][qt] = __builtin_amdgcn_mfma_f32_16x16x32_bf16(ak[kt], bq[qt], zero4, 0, 0, 0);

  bf16x4 ap16[2][4];   // [qt(=m2)][kt] A-fragments of normalized P
#pragma unroll
  for (int qt = 0; qt < 2; qt++) {
    float mx = -1e30f;
#pragma unroll
    for (int kt = 0; kt < 4; kt++)
#pragma unroll
      for (int r = 0; r < 4; r++) {
        float v = s[kt][qt][r];
        if (kt * 16 + g * 4 + r > 48) v = -1e30f;
        s[kt][qt][r] = v;
        mx = fmaxf(mx, v);
      }
    mx = fmaxf(mx, __shfl_xor(mx, 16));
    mx = fmaxf(mx, __shfl_xor(mx, 32));
    float sum = 0.f;
#pragma unroll
    for (int kt = 0; kt < 4; kt++)
#pragma unroll
      for (int r = 0; r < 4; r++) {
        float p = __expf(s[kt][qt][r] - mx);
        s[kt][qt][r] = p;
        sum += p;
      }
    sum += __shfl_xor(sum, 16);
    sum += __shfl_xor(sum, 32);
    float inv = 1.f / sum;
#pragma unroll
    for (int kt = 0; kt < 4; kt++)
      ap16[qt][kt] = pack4(s[kt][qt][0] * inv, s[kt][qt][1] * inv,
                           s[kt][qt][2] * inv, s[kt][qt][3] * inv);
  }

  // PV: 16x16x16 MFMAs, P straight from registers (no LDS, no barrier)
  f32x4 o[2][2] = {{zero4, zero4}, {zero4, zero4}};
#pragma unroll
  for (int kt = 0; kt < 4; kt++)
#pragma unroll
    for (int m2 = 0; m2 < 2; m2++)
#pragma unroll
      for (int nt2 = 0; nt2 < 2; nt2++)
        o[m2][nt2] = mfma16(ap16[m2][kt], bv16[nt2][kt], o[m2][nt2]);

  __syncthreads();   // bar4: all waves done reading Q/K/VT; ATT may overlay

#pragma unroll
  for (int m2 = 0; m2 < 2; m2++)
#pragma unroll
    for (int nt2 = 0; nt2 < 2; nt2++)
#pragma unroll
      for (int r = 0; r < 4; r++) {
        int tok = (half * 2 + m2) * 16 + g * 4 + r;
        int col = h * 32 + nt2 * 16 + l15;
        smem[ATT_OFF + tok * 128 + (col ^ ((tok & 7) << 3))] = f2bf(o[m2][nt2][r]);
      }
  __syncthreads();   // bar5: ATT complete

  // ---------- phase 4: proj + bias + store (fp32 out) ----------
  const int ccol = wave * 16 + l15;
  float biasp = bproj[ccol];
  f32x4 po[4] = {zero4, zero4, zero4, zero4};
#pragma unroll
  for (int kt = 0; kt < 4; kt++) {
    bf16x8 bwp = *(const bf16x8*)(wprojT + ccol * 128 + kt * 32 + g * 8);
#pragma unroll
    for (int mt = 0; mt < 4; mt++) {
      int row = mt * 16 + l15;
      int colE = kt * 32 + g * 8;
      bf16x8 aa = *(const bf16x8*)(&smem[ATT_OFF + row * 128 + (colE ^ ((row & 7) << 3))]);
      po[mt] = __builtin_amdgcn_mfma_f32_16x16x32_bf16(aa, bwp, po[mt], 0, 0, 0);
    }
  }
#pragma unroll
  for (int mt = 0; mt < 4; mt++)
#pragma unroll
    for (int r = 0; r < 4; r++) {
      int tok = mt * 16 + g * 4 + r;
      if (tok < 49) {
        size_t off = winbase + ((size_t)(tok / 7) * 112 + (tok % 7)) * 128 + ccol;
        out[off] = po[mt][r] + biasp;
      }
    }
}

extern "C" void kernel_launch(void* const* d_in, const int* in_sizes, int n_in,
                              void* d_out, int out_size, void* d_ws, size_t ws_size,
                              hipStream_t stream) {
  (void)in_sizes; (void)n_in; (void)out_size; (void)ws_size;
  const float* x     = (const float*)d_in[0];
  const float* wqkv  = (const float*)d_in[1];
  const float* bqkv  = (const float*)d_in[2];
  const float* wproj = (const float*)d_in[3];
  const float* bproj = (const float*)d_in[4];
  unsigned short* wt = (unsigned short*)d_ws;   // 131072 B: wqkvT + wprojT (bf16)

  hipLaunchKernelGGL(prep_weights, dim3(256), dim3(256), 0, stream, wqkv, wproj, wt);
  hipLaunchKernelGGL(win_attn, dim3(4096), dim3(TPB), 0, stream,
                     x, bqkv, bproj, wt, (float*)d_out);
}

// Round 11
// 103.534 us; speedup vs baseline: 1.0804x; 1.0804x over previous
//
#include <hip/hip_runtime.h>
#include <hip/hip_bf16.h>

typedef short bf16x8 __attribute__((ext_vector_type(8)));
typedef short bf16x4 __attribute__((ext_vector_type(4)));
typedef float f32x4 __attribute__((ext_vector_type(4)));
typedef unsigned short ushort8v __attribute__((ext_vector_type(8)));

#define TPB 512

// HW bf16 convert (RNE) — compiler emits v_cvt_pk_bf16_f32; do NOT hand-roll (r7/r8 lesson).
__device__ __forceinline__ unsigned short f2bf(float f) {
  __hip_bfloat16 h = __float2bfloat16(f);
  return __builtin_bit_cast(unsigned short, h);
}

__device__ __forceinline__ bf16x4 pack4(float a, float b, float c, float d) {
  bf16x4 v;
  v[0] = (short)f2bf(a); v[1] = (short)f2bf(b);
  v[2] = (short)f2bf(c); v[3] = (short)f2bf(d);
  return v;
}

// K=16 bf16 MFMA. A-frag k-pattern (k=4g+j) == D-layout row pattern (row=4g+r),
// so D-fragments feed K=16 MFMAs directly; with B = c*Identity it TRANSPOSES a
// 16x16 block in the matrix pipe (D = c*X^T + C), bias riding in on C.
__device__ __forceinline__ f32x4 mfma16(bf16x4 a, bf16x4 b, f32x4 c) {
#if __has_builtin(__builtin_amdgcn_mfma_f32_16x16x16_bf16)
  return __builtin_amdgcn_mfma_f32_16x16x16_bf16(a, b, c, 0, 0, 0);
#elif __has_builtin(__builtin_amdgcn_mfma_f32_16x16x16bf16_1k)
  return __builtin_amdgcn_mfma_f32_16x16x16bf16_1k(a, b, c, 0, 0, 0);
#else
  f32x4 d;
  asm("v_mfma_f32_16x16x16_bf16 %0, %1, %2, %3" : "=v"(d) : "v"(a), "v"(b), "v"(c));
  return d;
#endif
}

// LDS map (ushort element units) — overlaid lifetimes (usable LDS/CU = 128 KiB, r3-r7 fit):
//   [0..8192)      sWin [64][128] swizzled          (staging -> af regs)
//   [0..20480)     Q [4][64][40] + K [4][64][40]    (phase 1 -> ak/bq regs)  overlays sWin
//   [0..8192)      ATT [64][128] swizzled           (PV out -> proj)         overlays Q
//   [20480..29696) VT [4][32][72]                   (phase 1 -> bv regs)
#define Q_OFF   0
#define K_OFF   10240
#define ATT_OFF 0
#define VT_OFF  20480
#define SMEM_ELEMS 29696 // 59,392 B -> 2 blocks/CU (118,784 <= 131,072)

// scale * log2(e): softmax runs in log2 domain (exp2 instead of exp, saves 32 v_mul)
#define CQ 0.25501817f   // (1/sqrt(32)) * 1.4426950408889634

__global__ void prep_weights(const float* __restrict__ wqkv,
                             const float* __restrict__ wproj,
                             unsigned short* __restrict__ wt) {
  int idx = blockIdx.x * 256 + threadIdx.x;
  if (idx < 384 * 128) {                 // wqkvT[n][k] = bf16(wqkv[k][n])
    int n = idx >> 7, k = idx & 127;
    wt[idx] = f2bf(wqkv[k * 384 + n]);
  } else if (idx < 384 * 128 + 128 * 128) { // wprojT[c][k] = bf16(wproj[k][c])
    int j = idx - 384 * 128;
    int c = j >> 7, k = j & 127;
    wt[idx] = f2bf(wproj[k * 128 + c]);
  }
}

__launch_bounds__(TPB, 2)   // cap 128 VGPR; residency is LDS-pinned at 2 blocks/CU anyway
__global__ void win_attn(const float* __restrict__ x,
                         const float* __restrict__ bqkv,
                         const float* __restrict__ bproj,
                         const unsigned short* __restrict__ wt,
                         float* __restrict__ out) {
  __shared__ __align__(16) unsigned short smem[SMEM_ELEMS];
  const int tid  = threadIdx.x;
  const int wave = tid >> 6;
  const int lane = tid & 63;
  const int g    = lane >> 4;   // 16-lane group id (0..3)
  const int l15  = lane & 15;

  const int wid = blockIdx.x;
  const int b = wid >> 8, wh = (wid >> 4) & 15, ww = wid & 15;
  const size_t winbase = (((size_t)b * 112 + wh * 7) * 112 + ww * 7) * 128;

  const unsigned short* wqkvT  = wt;               // [384][128] bf16
  const unsigned short* wprojT = wt + 384 * 128;   // [128][128] bf16

  // identity B-frags for the transpose-mfma: B[k=4g+j][col=l15] = c * delta(4g+j, l15)
  bf16x4 idQ = {0, 0, 0, 0}, idK = {0, 0, 0, 0};
  if ((l15 >> 2) == g) {
    idQ[l15 & 3] = (short)f2bf(CQ);       // Q gets scale*log2e folded in
    idK[l15 & 3] = (short)0x3F80;         // 1.0 bf16
  }

  // ---------- stage window (fp32 -> bf16) -> sWin [64][128], XOR-swizzled (b128 writes) ----------
  for (int q = tid; q < 1024; q += TPB) {
    int row = q >> 4, c8 = q & 15;
    ushort8v v8 = {0, 0, 0, 0, 0, 0, 0, 0};
    if (row < 49) {
      const float4* src = (const float4*)(x + winbase + ((row / 7) * 112 + (row % 7)) * 128 + c8 * 8);
      float4 f0 = src[0], f1 = src[1];
      v8[0] = f2bf(f0.x); v8[1] = f2bf(f0.y); v8[2] = f2bf(f0.z); v8[3] = f2bf(f0.w);
      v8[4] = f2bf(f1.x); v8[5] = f2bf(f1.y); v8[6] = f2bf(f1.z); v8[7] = f2bf(f1.w);
    }
    int dst = row * 128 + ((c8 * 8) ^ ((row & 7) << 3));   // 16B-granule XOR: b128-safe
    *(ushort8v*)(&smem[dst]) = v8;
  }
  __syncthreads();   // bar1

  // ---------- phase 1: QKV = win @ w_qkv + b_qkv ----------
  bf16x8 af[4][4];
#pragma unroll
  for (int mt = 0; mt < 4; mt++)
#pragma unroll
    for (int kt = 0; kt < 4; kt++) {
      int row = mt * 16 + l15;
      int colE = kt * 32 + g * 8;
      af[mt][kt] = *(const bf16x8*)(&smem[row * 128 + (colE ^ ((row & 7) << 3))]);
    }
  __syncthreads();   // bar2: af in regs; Q/K/VT may now be written

  const f32x4 zero4 = {0.f, 0.f, 0.f, 0.f};

#pragma unroll
  for (int i = 0; i < 3; i++) {
    int nt = wave * 3 + i;          // 0..23 (n-tile of 384)
    int n  = nt * 16 + l15;         // output column

    bf16x8 bw[4];
#pragma unroll
    for (int kt = 0; kt < 4; kt++)
      bw[kt] = *(const bf16x8*)(wqkvT + n * 128 + kt * 32 + g * 8);

    f32x4 acc[4] = {zero4, zero4, zero4, zero4};
#pragma unroll
    for (int kt = 0; kt < 4; kt++)
#pragma unroll
      for (int mt = 0; mt < 4; mt++)
        acc[mt] = __builtin_amdgcn_mfma_f32_16x16x32_bf16(af[mt][kt], bw[kt], acc[mt], 0, 0, 0);

    int sec = nt >> 3;       // 0=Q 1=K 2=V  (uniform per (wave,i))
    if (sec == 2) {
      // V^T [d][tok]: D-layout already tok-in-regs -> packed ds_write_b64 (unchanged)
      float bias = bqkv[n];
      int hn = n & 127, h = hn >> 5, d = hn & 31;
#pragma unroll
      for (int mt = 0; mt < 4; mt++) {
        bf16x4 pv = pack4(acc[mt][0] + bias, acc[mt][1] + bias,
                          acc[mt][2] + bias, acc[mt][3] + bias);
        *(bf16x4*)(&smem[VT_OFF + h * 2304 + d * 72 + mt * 16 + g * 4]) = pv;
      }
    } else {
      // Q/K: transpose each 16x16 block via mfma16(A=pack(acc), B=c*I, C=c*bias).
      // Out: lane(l15,g) reg r = c*(X[tok=l15][d=4g+r] + bias[4g+r]) -> ushort4 write.
      int t7 = nt & 7;
      int hh = t7 >> 1, d0 = (t7 & 1) * 16;          // l15-independent head/d-offset
      const bf16x4 idf = (sec == 0) ? idQ : idK;
      const float  cf  = (sec == 0) ? CQ : 1.0f;
      float4 b4 = *(const float4*)(bqkv + nt * 16 + g * 4);   // bias for d = d0+4g..+3
      f32x4 c4; c4[0] = b4.x * cf; c4[1] = b4.y * cf; c4[2] = b4.z * cf; c4[3] = b4.w * cf;
      const int base = (sec == 0 ? Q_OFF : K_OFF) + hh * 2560 + d0 + g * 4;
#pragma unroll
      for (int mt = 0; mt < 4; mt++) {
        bf16x4 ax = pack4(acc[mt][0], acc[mt][1], acc[mt][2], acc[mt][3]);
        f32x4 dt = mfma16(ax, idf, c4);
        bf16x4 w = pack4(dt[0], dt[1], dt[2], dt[3]);
        *(bf16x4*)(&smem[base + (mt * 16 + l15) * 40]) = w;
      }
    }
  }
  __syncthreads();   // bar3: Q/K/VT complete

  // ---------- phase 2: attention, swapped QK^T (wave-pair per head) ----------
  // s = mfma(K, Qc): D col = q-token (l15), row-regs = k-token (kt*16 + 4g + r).
  // Q pre-scaled by scale*log2e -> softmax in log2 domain (exp2).
  const int h    = wave >> 1;
  const int half = wave & 1;        // query rows 0..31 or 32..63

  bf16x8 ak[4];
#pragma unroll
  for (int kt = 0; kt < 4; kt++) {
    int row = kt * 16 + l15;
    ak[kt] = *(const bf16x8*)(&smem[K_OFF + h * 2560 + row * 40 + g * 8]);
  }
  bf16x8 bq[2];
#pragma unroll
  for (int qt = 0; qt < 2; qt++) {
    int row = half * 32 + qt * 16 + l15;
    bq[qt] = *(const bf16x8*)(&smem[Q_OFF + h * 2560 + row * 40 + g * 8]);
  }
  // V B-frags for K=16 PV: B[k=4g+j][col=d=l15] = VT[d][tok=kt*16+4g+j]
  bf16x4 bv16[2][4];
#pragma unroll
  for (int nt2 = 0; nt2 < 2; nt2++)
#pragma unroll
    for (int kt = 0; kt < 4; kt++)
      bv16[nt2][kt] = *(const bf16x4*)(&smem[VT_OFF + h * 2304 + (nt2 * 16 + l15) * 72 + kt * 16 + g * 4]);

  f32x4 s[4][2];
#pragma unroll
  for (int kt = 0; kt < 4; kt++)
#pragma unroll
    for (int qt = 0; qt < 2; qt++)
      s[kt][qt] = __builtin_amdgcn_mfma_f32_16x16x32_bf16(ak[kt], bq[qt], zero4, 0, 0, 0);

  // softmax: only kt=3 needs masking (toks 48..63; tok 48 valid iff g==0 reg 0)
  bf16x4 ap16[2][4];   // [qt][kt] A-fragments of normalized P
  const bool v48 = (g == 0);
#pragma unroll
  for (int qt = 0; qt < 2; qt++) {
    float mx = -3e38f;
#pragma unroll
    for (int kt = 0; kt < 3; kt++)
#pragma unroll
      for (int r = 0; r < 4; r++) mx = fmaxf(mx, s[kt][qt][r]);
    float s3 = v48 ? s[3][qt][0] : -3e38f;
    mx = fmaxf(mx, s3);
    mx = fmaxf(mx, __shfl_xor(mx, 16));
    mx = fmaxf(mx, __shfl_xor(mx, 32));
    float sum = 0.f;
#pragma unroll
    for (int kt = 0; kt < 3; kt++)
#pragma unroll
      for (int r = 0; r < 4; r++) {
        float p = exp2f(s[kt][qt][r] - mx);
        s[kt][qt][r] = p;
        sum += p;
      }
    float p3 = v48 ? exp2f(s3 - mx) : 0.0f;
    sum += p3;
    sum += __shfl_xor(sum, 16);
    sum += __shfl_xor(sum, 32);
    float inv = 1.f / sum;
#pragma unroll
    for (int kt = 0; kt < 3; kt++)
      ap16[qt][kt] = pack4(s[kt][qt][0] * inv, s[kt][qt][1] * inv,
                           s[kt][qt][2] * inv, s[kt][qt][3] * inv);
    ap16[qt][3] = pack4(p3 * inv, 0.f, 0.f, 0.f);
  }

  // PV: 16x16x16 MFMAs, P straight from registers (no LDS, no barrier)
  f32x4 o[2][2] = {{zero4, zero4}, {zero4, zero4}};
#pragma unroll
  for (int kt = 0; kt < 4; kt++)
#pragma unroll
    for (int m2 = 0; m2 < 2; m2++)
#pragma unroll
      for (int nt2 = 0; nt2 < 2; nt2++)
        o[m2][nt2] = mfma16(ap16[m2][kt], bv16[nt2][kt], o[m2][nt2]);

  // hoist proj weight loads (global, independent of LDS state) above the barriers
  const int ccol = wave * 16 + l15;
  bf16x8 bwp[4];
#pragma unroll
  for (int kt = 0; kt < 4; kt++)
    bwp[kt] = *(const bf16x8*)(wprojT + ccol * 128 + kt * 32 + g * 8);
  float biasp = bproj[ccol];

  __syncthreads();   // bar4: all waves done reading Q/K/VT; ATT may overlay

#pragma unroll
  for (int m2 = 0; m2 < 2; m2++)
#pragma unroll
    for (int nt2 = 0; nt2 < 2; nt2++)
#pragma unroll
      for (int r = 0; r < 4; r++) {
        int tok = (half * 2 + m2) * 16 + g * 4 + r;
        int col = h * 32 + nt2 * 16 + l15;
        smem[ATT_OFF + tok * 128 + (col ^ ((tok & 7) << 3))] = f2bf(o[m2][nt2][r]);
      }
  __syncthreads();   // bar5: ATT complete

  // ---------- phase 4: proj + bias + store (fp32 out) ----------
  f32x4 po[4] = {zero4, zero4, zero4, zero4};
#pragma unroll
  for (int kt = 0; kt < 4; kt++) {
#pragma unroll
    for (int mt = 0; mt < 4; mt++) {
      int row = mt * 16 + l15;
      int colE = kt * 32 + g * 8;
      bf16x8 aa = *(const bf16x8*)(&smem[ATT_OFF + row * 128 + (colE ^ ((row & 7) << 3))]);
      po[mt] = __builtin_amdgcn_mfma_f32_16x16x32_bf16(aa, bwp[kt], po[mt], 0, 0, 0);
    }
  }
#pragma unroll
  for (int mt = 0; mt < 4; mt++)
#pragma unroll
    for (int r = 0; r < 4; r++) {
      int tok = mt * 16 + g * 4 + r;
      if (tok < 49) {
        size_t off = winbase + ((size_t)(tok / 7) * 112 + (tok % 7)) * 128 + ccol;
        out[off] = po[mt][r] + biasp;
      }
    }
}

extern "C" void kernel_launch(void* const* d_in, const int* in_sizes, int n_in,
                              void* d_out, int out_size, void* d_ws, size_t ws_size,
                              hipStream_t stream) {
  (void)in_sizes; (void)n_in; (void)out_size; (void)ws_size;
  const float* x     = (const float*)d_in[0];
  const float* wqkv  = (const float*)d_in[1];
  const float* bqkv  = (const float*)d_in[2];
  const float* wproj = (const float*)d_in[3];
  const float* bproj = (const float*)d_in[4];
  unsigned short* wt = (unsigned short*)d_ws;   // 131072 B: wqkvT + wprojT (bf16)

  hipLaunchKernelGGL(prep_weights, dim3(256), dim3(256), 0, stream, wqkv, wproj, wt);
  hipLaunchKernelGGL(win_attn, dim3(4096), dim3(TPB), 0, stream,
                     x, bqkv, bproj, wt, (float*)d_out);
}

// Round 12
// 101.509 us; speedup vs baseline: 1.1020x; 1.0199x over previous
//
#include <hip/hip_runtime.h>
#include <hip/hip_bf16.h>

typedef short bf16x8 __attribute__((ext_vector_type(8)));
typedef short bf16x4 __attribute__((ext_vector_type(4)));
typedef float f32x4 __attribute__((ext_vector_type(4)));
typedef unsigned short ushort8v __attribute__((ext_vector_type(8)));

#define TPB 512

// HW bf16 convert (RNE) — compiler emits v_cvt_pk_bf16_f32; do NOT hand-roll (r7/r8 lesson).
__device__ __forceinline__ unsigned short f2bf(float f) {
  __hip_bfloat16 h = __float2bfloat16(f);
  return __builtin_bit_cast(unsigned short, h);
}

__device__ __forceinline__ bf16x4 pack4(float a, float b, float c, float d) {
  bf16x4 v;
  v[0] = (short)f2bf(a); v[1] = (short)f2bf(b);
  v[2] = (short)f2bf(c); v[3] = (short)f2bf(d);
  return v;
}

// K=16 bf16 MFMA. A-frag k-pattern (k=4g+j) == D-layout row pattern (row=4g+r),
// so D-fragments feed K=16 MFMAs directly; with B = c*Identity it TRANSPOSES a
// 16x16 block in the matrix pipe (D = c*X^T).
__device__ __forceinline__ f32x4 mfma16(bf16x4 a, bf16x4 b, f32x4 c) {
#if __has_builtin(__builtin_amdgcn_mfma_f32_16x16x16_bf16)
  return __builtin_amdgcn_mfma_f32_16x16x16_bf16(a, b, c, 0, 0, 0);
#elif __has_builtin(__builtin_amdgcn_mfma_f32_16x16x16bf16_1k)
  return __builtin_amdgcn_mfma_f32_16x16x16bf16_1k(a, b, c, 0, 0, 0);
#else
  f32x4 d;
  asm("v_mfma_f32_16x16x16_bf16 %0, %1, %2, %3" : "=v"(d) : "v"(a), "v"(b), "v"(c));
  return d;
#endif
}

// LDS map (ushort element units) — overlaid lifetimes (usable LDS/CU = 128 KiB, r3-r7 fit):
//   [0..8192)      sWin [64][128] swizzled          (staging -> af regs)
//   [0..20480)     Q [4][64][40] + K [4][64][40]    (phase 1 -> ak/bq regs)  overlays sWin
//   [0..8192)      ATT [64][128] swizzled           (PV out -> proj)         overlays Q
//   [20480..29696) VT [4][32][72]                   (phase 1 -> bv regs)
#define Q_OFF   0
#define K_OFF   10240
#define ATT_OFF 0
#define VT_OFF  20480
#define SMEM_ELEMS 29696 // 59,392 B -> 2 blocks/CU (118,784 <= 131,072)

// scale * log2(e): softmax runs in log2 domain. Logits are tiny (|s|<~2) so the
// max-subtraction is omitted entirely — exp2(s)/sum(exp2(s)) is ratio-exact.
#define CQ 0.25501817f   // (1/sqrt(32)) * 1.4426950408889634

__global__ void prep_weights(const float* __restrict__ wqkv,
                             const float* __restrict__ wproj,
                             unsigned short* __restrict__ wt) {
  int idx = blockIdx.x * 256 + threadIdx.x;
  if (idx < 384 * 128) {                 // wqkvT[n][k] = bf16(wqkv[k][n])
    int n = idx >> 7, k = idx & 127;
    wt[idx] = f2bf(wqkv[k * 384 + n]);
  } else if (idx < 384 * 128 + 128 * 128) { // wprojT[c][k] = bf16(wproj[k][c])
    int j = idx - 384 * 128;
    int c = j >> 7, k = j & 127;
    wt[idx] = f2bf(wproj[k * 128 + c]);
  }
}

__launch_bounds__(TPB, 2)   // cap 128 VGPR; residency is LDS-pinned at 2 blocks/CU anyway
__global__ void win_attn(const float* __restrict__ x,
                         const float* __restrict__ bqkv,
                         const float* __restrict__ bproj,
                         const unsigned short* __restrict__ wt,
                         float* __restrict__ out) {
  __shared__ __align__(16) unsigned short smem[SMEM_ELEMS];
  const int tid  = threadIdx.x;
  const int wave = tid >> 6;
  const int lane = tid & 63;
  const int g    = lane >> 4;   // 16-lane group id (0..3)
  const int l15  = lane & 15;

  const int wid = blockIdx.x;
  const int b = wid >> 8, wh = (wid >> 4) & 15, ww = wid & 15;
  const size_t winbase = (((size_t)b * 112 + wh * 7) * 112 + ww * 7) * 128;

  const unsigned short* wqkvT  = wt;               // [384][128] bf16
  const unsigned short* wprojT = wt + 384 * 128;   // [128][128] bf16

  // identity B-frags for the transpose-mfma: B[k=4g+j][col=l15] = c * delta(4g+j, l15)
  bf16x4 idQ = {0, 0, 0, 0}, idK = {0, 0, 0, 0};
  if ((l15 >> 2) == g) {
    idQ[l15 & 3] = (short)f2bf(CQ);       // Q gets scale*log2e folded in
    idK[l15 & 3] = (short)0x3F80;         // 1.0 bf16
  }

  // ---------- stage window (fp32 -> bf16) -> sWin [64][128], XOR-swizzled ----------
  // rows 49..63: clamped copy of row 48 (finite garbage is safe: Q rows discarded,
  // K toks masked in softmax, V toks killed by P=0) — no divergent zero branch.
  for (int q = tid; q < 1024; q += TPB) {
    int row = q >> 4, c8 = q & 15;
    int rowc = min(row, 48);
    const float4* src = (const float4*)(x + winbase + ((rowc / 7) * 112 + (rowc % 7)) * 128 + c8 * 8);
    float4 f0 = src[0], f1 = src[1];
    ushort8v v8;
    v8[0] = f2bf(f0.x); v8[1] = f2bf(f0.y); v8[2] = f2bf(f0.z); v8[3] = f2bf(f0.w);
    v8[4] = f2bf(f1.x); v8[5] = f2bf(f1.y); v8[6] = f2bf(f1.z); v8[7] = f2bf(f1.w);
    int dst = row * 128 + ((c8 * 8) ^ ((row & 7) << 3));   // 16B-granule XOR: b128-safe
    *(ushort8v*)(&smem[dst]) = v8;
  }
  __syncthreads();   // bar1

  // ---------- phase 1: QKV = win @ w_qkv + b_qkv ----------
  bf16x8 af[4][4];
#pragma unroll
  for (int mt = 0; mt < 4; mt++)
#pragma unroll
    for (int kt = 0; kt < 4; kt++) {
      int row = mt * 16 + l15;
      int colE = kt * 32 + g * 8;
      af[mt][kt] = *(const bf16x8*)(&smem[row * 128 + (colE ^ ((row & 7) << 3))]);
    }
  __syncthreads();   // bar2: af in regs; Q/K/VT may now be written

  const f32x4 zero4 = {0.f, 0.f, 0.f, 0.f};

#pragma unroll
  for (int i = 0; i < 3; i++) {
    int nt = wave * 3 + i;          // 0..23 (n-tile of 384)
    int n  = nt * 16 + l15;         // output column
    float bias = bqkv[n];
    f32x4 binit = {bias, bias, bias, bias};   // bias rides in on the MFMA C operand

    bf16x8 bw[4];
#pragma unroll
    for (int kt = 0; kt < 4; kt++)
      bw[kt] = *(const bf16x8*)(wqkvT + n * 128 + kt * 32 + g * 8);

    f32x4 acc[4] = {binit, binit, binit, binit};
    __builtin_amdgcn_s_setprio(1);
#pragma unroll
    for (int kt = 0; kt < 4; kt++)
#pragma unroll
      for (int mt = 0; mt < 4; mt++)
        acc[mt] = __builtin_amdgcn_mfma_f32_16x16x32_bf16(af[mt][kt], bw[kt], acc[mt], 0, 0, 0);
    __builtin_amdgcn_s_setprio(0);

    int sec = nt >> 3;       // 0=Q 1=K 2=V  (uniform per (wave,i))
    if (sec == 2) {
      // V^T [d][tok]: D-layout already tok-in-regs -> packed ds_write_b64 (bias already in)
      int hn = n & 127, h = hn >> 5, d = hn & 31;
#pragma unroll
      for (int mt = 0; mt < 4; mt++) {
        bf16x4 pv = pack4(acc[mt][0], acc[mt][1], acc[mt][2], acc[mt][3]);
        *(bf16x4*)(&smem[VT_OFF + h * 2304 + d * 72 + mt * 16 + g * 4]) = pv;
      }
    } else {
      // Q/K: transpose each 16x16 block via mfma16(A=pack(acc), B=c*I, C=0).
      // Out: lane(l15,g) reg r = c*(X+bias)[tok=l15][d=4g+r] -> ushort4 write.
      int t7 = nt & 7;
      int hh = t7 >> 1, d0 = (t7 & 1) * 16;          // l15-independent head/d-offset
      const bf16x4 idf = (sec == 0) ? idQ : idK;
      const int base = (sec == 0 ? Q_OFF : K_OFF) + hh * 2560 + d0 + g * 4;
#pragma unroll
      for (int mt = 0; mt < 4; mt++) {
        bf16x4 ax = pack4(acc[mt][0], acc[mt][1], acc[mt][2], acc[mt][3]);
        f32x4 dt = mfma16(ax, idf, zero4);
        bf16x4 w = pack4(dt[0], dt[1], dt[2], dt[3]);
        *(bf16x4*)(&smem[base + (mt * 16 + l15) * 40]) = w;
      }
    }
  }
  __syncthreads();   // bar3: Q/K/VT complete

  // ---------- phase 2: attention, swapped QK^T (wave-pair per head) ----------
  // s = mfma(K, Qc): D col = q-token (l15), row-regs = k-token (kt*16 + 4g + r).
  const int h    = wave >> 1;
  const int half = wave & 1;        // query rows 0..31 or 32..63

  bf16x8 ak[4];
#pragma unroll
  for (int kt = 0; kt < 4; kt++) {
    int row = kt * 16 + l15;
    ak[kt] = *(const bf16x8*)(&smem[K_OFF + h * 2560 + row * 40 + g * 8]);
  }
  bf16x8 bq[2];
#pragma unroll
  for (int qt = 0; qt < 2; qt++) {
    int row = half * 32 + qt * 16 + l15;
    bq[qt] = *(const bf16x8*)(&smem[Q_OFF + h * 2560 + row * 40 + g * 8]);
  }
  // V B-frags for K=16 PV: B[k=4g+j][col=d=l15] = VT[d][tok=kt*16+4g+j]
  bf16x4 bv16[2][4];
#pragma unroll
  for (int nt2 = 0; nt2 < 2; nt2++)
#pragma unroll
    for (int kt = 0; kt < 4; kt++)
      bv16[nt2][kt] = *(const bf16x4*)(&smem[VT_OFF + h * 2304 + (nt2 * 16 + l15) * 72 + kt * 16 + g * 4]);

  f32x4 s[4][2];
  __builtin_amdgcn_s_setprio(1);
#pragma unroll
  for (int kt = 0; kt < 4; kt++)
#pragma unroll
    for (int qt = 0; qt < 2; qt++)
      s[kt][qt] = __builtin_amdgcn_mfma_f32_16x16x32_bf16(ak[kt], bq[qt], zero4, 0, 0, 0);
  __builtin_amdgcn_s_setprio(0);

  // softmax WITHOUT max-subtraction (logits tiny; exp2 overflow-safe) —
  // only kt=3 needs masking (toks 48..63; tok 48 valid iff g==0 reg 0)
  bf16x4 ap16[2][4];   // [qt][kt] A-fragments of normalized P
  const bool v48 = (g == 0);
#pragma unroll
  for (int qt = 0; qt < 2; qt++) {
    float sum = 0.f;
#pragma unroll
    for (int kt = 0; kt < 3; kt++)
#pragma unroll
      for (int r = 0; r < 4; r++) {
        float p = exp2f(s[kt][qt][r]);
        s[kt][qt][r] = p;
        sum += p;
      }
    float p3 = v48 ? exp2f(s[3][qt][0]) : 0.0f;
    sum += p3;
    sum += __shfl_xor(sum, 16);
    sum += __shfl_xor(sum, 32);
    float inv = 1.f / sum;
#pragma unroll
    for (int kt = 0; kt < 3; kt++)
      ap16[qt][kt] = pack4(s[kt][qt][0] * inv, s[kt][qt][1] * inv,
                           s[kt][qt][2] * inv, s[kt][qt][3] * inv);
    ap16[qt][3] = pack4(p3 * inv, 0.f, 0.f, 0.f);
  }

  // PV: 16x16x16 MFMAs, P straight from registers (no LDS, no barrier)
  f32x4 o[2][2] = {{zero4, zero4}, {zero4, zero4}};
  __builtin_amdgcn_s_setprio(1);
#pragma unroll
  for (int kt = 0; kt < 4; kt++)
#pragma unroll
    for (int m2 = 0; m2 < 2; m2++)
#pragma unroll
      for (int nt2 = 0; nt2 < 2; nt2++)
        o[m2][nt2] = mfma16(ap16[m2][kt], bv16[nt2][kt], o[m2][nt2]);
  __builtin_amdgcn_s_setprio(0);

  // hoist proj weight loads (global, independent of LDS state) above the barriers
  const int ccol = wave * 16 + l15;
  bf16x8 bwp[4];
#pragma unroll
  for (int kt = 0; kt < 4; kt++)
    bwp[kt] = *(const bf16x8*)(wprojT + ccol * 128 + kt * 32 + g * 8);
  float biasp = bproj[ccol];

  __syncthreads();   // bar4: all waves done reading Q/K/VT; ATT may overlay

#pragma unroll
  for (int m2 = 0; m2 < 2; m2++)
#pragma unroll
    for (int nt2 = 0; nt2 < 2; nt2++)
#pragma unroll
      for (int r = 0; r < 4; r++) {
        int tok = (half * 2 + m2) * 16 + g * 4 + r;
        int col = h * 32 + nt2 * 16 + l15;
        smem[ATT_OFF + tok * 128 + (col ^ ((tok & 7) << 3))] = f2bf(o[m2][nt2][r]);
      }
  __syncthreads();   // bar5: ATT complete

  // ---------- phase 4: proj + bias + store (fp32 out) ----------
  f32x4 po[4] = {zero4, zero4, zero4, zero4};
  __builtin_amdgcn_s_setprio(1);
#pragma unroll
  for (int kt = 0; kt < 4; kt++) {
#pragma unroll
    for (int mt = 0; mt < 4; mt++) {
      int row = mt * 16 + l15;
      int colE = kt * 32 + g * 8;
      bf16x8 aa = *(const bf16x8*)(&smem[ATT_OFF + row * 128 + (colE ^ ((row & 7) << 3))]);
      po[mt] = __builtin_amdgcn_mfma_f32_16x16x32_bf16(aa, bwp[kt], po[mt], 0, 0, 0);
    }
  }
  __builtin_amdgcn_s_setprio(0);
#pragma unroll
  for (int mt = 0; mt < 4; mt++)
#pragma unroll
    for (int r = 0; r < 4; r++) {
      int tok = mt * 16 + g * 4 + r;
      if (tok < 49) {
        size_t off = winbase + ((size_t)(tok / 7) * 112 + (tok % 7)) * 128 + ccol;
        out[off] = po[mt][r] + biasp;
      }
    }
}

extern "C" void kernel_launch(void* const* d_in, const int* in_sizes, int n_in,
                              void* d_out, int out_size, void* d_ws, size_t ws_size,
                              hipStream_t stream) {
  (void)in_sizes; (void)n_in; (void)out_size; (void)ws_size;
  const float* x     = (const float*)d_in[0];
  const float* wqkv  = (const float*)d_in[1];
  const float* bqkv  = (const float*)d_in[2];
  const float* wproj = (const float*)d_in[3];
  const float* bproj = (const float*)d_in[4];
  unsigned short* wt = (unsigned short*)d_ws;   // 131072 B: wqkvT + wprojT (bf16)

  hipLaunchKernelGGL(prep_weights, dim3(256), dim3(256), 0, stream, wqkv, wproj, wt);
  hipLaunchKernelGGL(win_attn, dim3(4096), dim3(TPB), 0, stream,
                     x, bqkv, bproj, wt, (float*)d_out);
}

// Round 13
// 95.570 us; speedup vs baseline: 1.1704x; 1.0621x over previous
//
#include <hip/hip_runtime.h>
#include <hip/hip_bf16.h>

typedef short bf16x8 __attribute__((ext_vector_type(8)));
typedef short bf16x4 __attribute__((ext_vector_type(4)));
typedef float f32x4 __attribute__((ext_vector_type(4)));
typedef unsigned short ushort8v __attribute__((ext_vector_type(8)));

#define TPB 512

// HW bf16 convert (RNE) — compiler emits v_cvt_pk_bf16_f32; do NOT hand-roll (r7/r8 lesson).
__device__ __forceinline__ unsigned short f2bf(float f) {
  __hip_bfloat16 h = __float2bfloat16(f);
  return __builtin_bit_cast(unsigned short, h);
}

__device__ __forceinline__ bf16x4 pack4(float a, float b, float c, float d) {
  bf16x4 v;
  v[0] = (short)f2bf(a); v[1] = (short)f2bf(b);
  v[2] = (short)f2bf(c); v[3] = (short)f2bf(d);
  return v;
}

// K=16 bf16 MFMA. A-frag k-pattern (k=4g+j) == D-layout row pattern (row=4g+r),
// so D-fragments feed K=16 MFMAs directly; with B = c*Identity it TRANSPOSES a
// 16x16 block in the matrix pipe (D = c*X^T).
__device__ __forceinline__ f32x4 mfma16(bf16x4 a, bf16x4 b, f32x4 c) {
#if __has_builtin(__builtin_amdgcn_mfma_f32_16x16x16_bf16)
  return __builtin_amdgcn_mfma_f32_16x16x16_bf16(a, b, c, 0, 0, 0);
#elif __has_builtin(__builtin_amdgcn_mfma_f32_16x16x16bf16_1k)
  return __builtin_amdgcn_mfma_f32_16x16x16bf16_1k(a, b, c, 0, 0, 0);
#else
  f32x4 d;
  asm("v_mfma_f32_16x16x16_bf16 %0, %1, %2, %3" : "=v"(d) : "v"(a), "v"(b), "v"(c));
  return d;
#endif
}

// raw v_exp_f32 / v_rcp_f32 — skip ocml edge-case wrappers (r12: ~4x VALU bloat vs hand count;
// inputs here are bounded so raw HW approx instrs are safe within the 2e-3 budget)
__device__ __forceinline__ float exp2_raw(float x) {
#if __has_builtin(__builtin_amdgcn_exp2f)
  return __builtin_amdgcn_exp2f(x);
#else
  float r; asm("v_exp_f32 %0, %1" : "=v"(r) : "v"(x)); return r;
#endif
}
__device__ __forceinline__ float rcp_raw(float x) {
#if __has_builtin(__builtin_amdgcn_rcpf)
  return __builtin_amdgcn_rcpf(x);
#else
  float r; asm("v_rcp_f32 %0, %1" : "=v"(r) : "v"(x)); return r;
#endif
}

// LDS map (ushort element units) — overlaid lifetimes (usable LDS/CU = 128 KiB, r3-r7 fit):
//   [0..8192)      sWin [64][128] swizzled          (staging -> af regs)
//   [0..20480)     Q [4][64][40] + K [4][64][40]    (phase 1 -> ak/bq regs)  overlays sWin
//   [0..8192)      ATT [64][128] swizzled           (PV out -> proj)         overlays Q
//   [20480..29696) VT [4][32][72]                   (phase 1 -> bv regs)
#define Q_OFF   0
#define K_OFF   10240
#define ATT_OFF 0
#define VT_OFF  20480
#define SMEM_ELEMS 29696 // 59,392 B -> 2 blocks/CU (118,784 <= 131,072)

// scale * log2(e): softmax runs in log2 domain. Logits are tiny (|s|<~2) so the
// max-subtraction is omitted entirely — exp2(s)/sum(exp2(s)) is ratio-exact.
#define CQ 0.25501817f   // (1/sqrt(32)) * 1.4426950408889634

__global__ void prep_weights(const float* __restrict__ wqkv,
                             const float* __restrict__ wproj,
                             unsigned short* __restrict__ wt) {
  int idx = blockIdx.x * 256 + threadIdx.x;
  if (idx < 384 * 128) {                 // wqkvT[n][k] = bf16(wqkv[k][n])
    int n = idx >> 7, k = idx & 127;
    wt[idx] = f2bf(wqkv[k * 384 + n]);
  } else if (idx < 384 * 128 + 128 * 128) { // wprojT[c][k] = bf16(wproj[k][c])
    int j = idx - 384 * 128;
    int c = j >> 7, k = j & 127;
    wt[idx] = f2bf(wproj[k * 128 + c]);
  }
}

__launch_bounds__(TPB, 2)   // cap 128 VGPR; residency is LDS-pinned at 2 blocks/CU anyway
__global__ void win_attn(const float* __restrict__ x,
                         const float* __restrict__ bqkv,
                         const float* __restrict__ bproj,
                         const unsigned short* __restrict__ wt,
                         float* __restrict__ out) {
  __shared__ __align__(16) unsigned short smem[SMEM_ELEMS];
  const int tid  = threadIdx.x;
  const int wave = tid >> 6;
  const int lane = tid & 63;
  const int g    = lane >> 4;   // 16-lane group id (0..3)
  const int l15  = lane & 15;

  const int wid = blockIdx.x;
  const int b = wid >> 8, wh = (wid >> 4) & 15, ww = wid & 15;
  const size_t winbase = (((size_t)b * 112 + wh * 7) * 112 + ww * 7) * 128;

  const unsigned short* wqkvT  = wt;               // [384][128] bf16
  const unsigned short* wprojT = wt + 384 * 128;   // [128][128] bf16

  // identity B-frags for the transpose-mfma: B[k=4g+j][col=l15] = c * delta(4g+j, l15)
  bf16x4 idQ = {0, 0, 0, 0}, idK = {0, 0, 0, 0};
  if ((l15 >> 2) == g) {
    idQ[l15 & 3] = (short)f2bf(CQ);       // Q gets scale*log2e folded in
    idK[l15 & 3] = (short)0x3F80;         // 1.0 bf16
  }

  // ---------- stage window (fp32 -> bf16) -> sWin [64][128], XOR-swizzled ----------
  // rows 49..63: clamped copy of row 48 (finite garbage is safe: Q rows discarded,
  // K toks masked in softmax, V toks killed by P=0) — no divergent zero branch.
  for (int q = tid; q < 1024; q += TPB) {
    int row = q >> 4, c8 = q & 15;
    int rowc = min(row, 48);
    const float4* src = (const float4*)(x + winbase + ((rowc / 7) * 112 + (rowc % 7)) * 128 + c8 * 8);
    float4 f0 = src[0], f1 = src[1];
    ushort8v v8;
    v8[0] = f2bf(f0.x); v8[1] = f2bf(f0.y); v8[2] = f2bf(f0.z); v8[3] = f2bf(f0.w);
    v8[4] = f2bf(f1.x); v8[5] = f2bf(f1.y); v8[6] = f2bf(f1.z); v8[7] = f2bf(f1.w);
    int dst = row * 128 + ((c8 * 8) ^ ((row & 7) << 3));   // 16B-granule XOR: b128-safe
    *(ushort8v*)(&smem[dst]) = v8;
  }
  __syncthreads();   // bar1

  // ---------- phase 1: QKV = win @ w_qkv + b_qkv ----------
  bf16x8 af[4][4];
#pragma unroll
  for (int mt = 0; mt < 4; mt++)
#pragma unroll
    for (int kt = 0; kt < 4; kt++) {
      int row = mt * 16 + l15;
      int colE = kt * 32 + g * 8;
      af[mt][kt] = *(const bf16x8*)(&smem[row * 128 + (colE ^ ((row & 7) << 3))]);
    }
  __syncthreads();   // bar2: af in regs; Q/K/VT may now be written

  const f32x4 zero4 = {0.f, 0.f, 0.f, 0.f};

#pragma unroll
  for (int i = 0; i < 3; i++) {
    int nt = wave * 3 + i;          // 0..23 (n-tile of 384)
    int n  = nt * 16 + l15;         // output column
    float bias = bqkv[n];
    f32x4 binit = {bias, bias, bias, bias};   // bias rides in on the MFMA C operand

    bf16x8 bw[4];
#pragma unroll
    for (int kt = 0; kt < 4; kt++)
      bw[kt] = *(const bf16x8*)(wqkvT + n * 128 + kt * 32 + g * 8);

    f32x4 acc[4] = {binit, binit, binit, binit};
    __builtin_amdgcn_s_setprio(1);
#pragma unroll
    for (int kt = 0; kt < 4; kt++)
#pragma unroll
      for (int mt = 0; mt < 4; mt++)
        acc[mt] = __builtin_amdgcn_mfma_f32_16x16x32_bf16(af[mt][kt], bw[kt], acc[mt], 0, 0, 0);
    __builtin_amdgcn_s_setprio(0);

    int sec = nt >> 3;       // 0=Q 1=K 2=V  (uniform per (wave,i))
    if (sec == 2) {
      // V^T [d][tok]: D-layout already tok-in-regs -> packed ds_write_b64 (bias already in)
      int hn = n & 127, h = hn >> 5, d = hn & 31;
#pragma unroll
      for (int mt = 0; mt < 4; mt++) {
        bf16x4 pv = pack4(acc[mt][0], acc[mt][1], acc[mt][2], acc[mt][3]);
        *(bf16x4*)(&smem[VT_OFF + h * 2304 + d * 72 + mt * 16 + g * 4]) = pv;
      }
    } else {
      // Q/K: transpose each 16x16 block via mfma16(A=pack(acc), B=c*I, C=0).
      // Out: lane(l15,g) reg r = c*(X+bias)[tok=l15][d=4g+r] -> ushort4 write.
      int t7 = nt & 7;
      int hh = t7 >> 1, d0 = (t7 & 1) * 16;          // l15-independent head/d-offset
      const bf16x4 idf = (sec == 0) ? idQ : idK;
      const int base = (sec == 0 ? Q_OFF : K_OFF) + hh * 2560 + d0 + g * 4;
#pragma unroll
      for (int mt = 0; mt < 4; mt++) {
        bf16x4 ax = pack4(acc[mt][0], acc[mt][1], acc[mt][2], acc[mt][3]);
        f32x4 dt = mfma16(ax, idf, zero4);
        bf16x4 w = pack4(dt[0], dt[1], dt[2], dt[3]);
        *(bf16x4*)(&smem[base + (mt * 16 + l15) * 40]) = w;
      }
    }
  }
  __syncthreads();   // bar3: Q/K/VT complete

  // ---------- phase 2: attention, swapped QK^T (wave-pair per head) ----------
  // s = mfma(K, Qc): D col = q-token (l15), row-regs = k-token (kt*16 + 4g + r).
  const int h    = wave >> 1;
  const int half = wave & 1;        // query rows 0..31 or 32..63

  bf16x8 ak[4];
#pragma unroll
  for (int kt = 0; kt < 4; kt++) {
    int row = kt * 16 + l15;
    ak[kt] = *(const bf16x8*)(&smem[K_OFF + h * 2560 + row * 40 + g * 8]);
  }
  bf16x8 bq[2];
#pragma unroll
  for (int qt = 0; qt < 2; qt++) {
    int row = half * 32 + qt * 16 + l15;
    bq[qt] = *(const bf16x8*)(&smem[Q_OFF + h * 2560 + row * 40 + g * 8]);
  }
  // V B-frags for K=16 PV: B[k=4g+j][col=d=l15] = VT[d][tok=kt*16+4g+j]
  bf16x4 bv16[2][4];
#pragma unroll
  for (int nt2 = 0; nt2 < 2; nt2++)
#pragma unroll
    for (int kt = 0; kt < 4; kt++)
      bv16[nt2][kt] = *(const bf16x4*)(&smem[VT_OFF + h * 2304 + (nt2 * 16 + l15) * 72 + kt * 16 + g * 4]);

  f32x4 s[4][2];
  __builtin_amdgcn_s_setprio(1);
#pragma unroll
  for (int kt = 0; kt < 4; kt++)
#pragma unroll
    for (int qt = 0; qt < 2; qt++)
      s[kt][qt] = __builtin_amdgcn_mfma_f32_16x16x32_bf16(ak[kt], bq[qt], zero4, 0, 0, 0);
  __builtin_amdgcn_s_setprio(0);

  // softmax WITHOUT max-subtraction (logits tiny; exp2 overflow-safe) —
  // only kt=3 needs masking (toks 48..63; tok 48 valid iff g==0 reg 0)
  bf16x4 ap16[2][4];   // [qt][kt] A-fragments of normalized P
  const bool v48 = (g == 0);
#pragma unroll
  for (int qt = 0; qt < 2; qt++) {
    float sum = 0.f;
#pragma unroll
    for (int kt = 0; kt < 3; kt++)
#pragma unroll
      for (int r = 0; r < 4; r++) {
        float p = exp2_raw(s[kt][qt][r]);
        s[kt][qt][r] = p;
        sum += p;
      }
    float p3 = v48 ? exp2_raw(s[3][qt][0]) : 0.0f;
    sum += p3;
    sum += __shfl_xor(sum, 16);
    sum += __shfl_xor(sum, 32);
    float inv = rcp_raw(sum);
#pragma unroll
    for (int kt = 0; kt < 3; kt++)
      ap16[qt][kt] = pack4(s[kt][qt][0] * inv, s[kt][qt][1] * inv,
                           s[kt][qt][2] * inv, s[kt][qt][3] * inv);
    ap16[qt][3] = pack4(p3 * inv, 0.f, 0.f, 0.f);
  }

  // PV: 16x16x16 MFMAs, P straight from registers (no LDS, no barrier)
  f32x4 o[2][2] = {{zero4, zero4}, {zero4, zero4}};
  __builtin_amdgcn_s_setprio(1);
#pragma unroll
  for (int kt = 0; kt < 4; kt++)
#pragma unroll
    for (int m2 = 0; m2 < 2; m2++)
#pragma unroll
      for (int nt2 = 0; nt2 < 2; nt2++)
        o[m2][nt2] = mfma16(ap16[m2][kt], bv16[nt2][kt], o[m2][nt2]);
  __builtin_amdgcn_s_setprio(0);

  // transpose O tiles in the matrix pipe (reg-only, before bar4):
  // lane then holds O[tok=l15][d=4g+r] -> one b64 LDS write per tile.
  bf16x4 attw[2][2];
#pragma unroll
  for (int m2 = 0; m2 < 2; m2++)
#pragma unroll
    for (int nt2 = 0; nt2 < 2; nt2++) {
      bf16x4 ox = pack4(o[m2][nt2][0], o[m2][nt2][1], o[m2][nt2][2], o[m2][nt2][3]);
      f32x4 ot = mfma16(ox, idK, zero4);
      attw[m2][nt2] = pack4(ot[0], ot[1], ot[2], ot[3]);
    }

  // hoist proj weight loads (global, independent of LDS state) above the barriers
  const int ccol = wave * 16 + l15;
  bf16x8 bwp[4];
#pragma unroll
  for (int kt = 0; kt < 4; kt++)
    bwp[kt] = *(const bf16x8*)(wprojT + ccol * 128 + kt * 32 + g * 8);
  float biasp = bproj[ccol];

  __syncthreads();   // bar4: all waves done reading Q/K/VT; ATT may overlay

#pragma unroll
  for (int m2 = 0; m2 < 2; m2++)
#pragma unroll
    for (int nt2 = 0; nt2 < 2; nt2++) {
      int tok  = (half * 2 + m2) * 16 + l15;
      int col0 = h * 32 + nt2 * 16 + g * 4;
      *(bf16x4*)(&smem[ATT_OFF + tok * 128 + (col0 ^ ((tok & 7) << 3))]) = attw[m2][nt2];
    }
  __syncthreads();   // bar5: ATT complete

  // ---------- phase 4: proj + bias + store (fp32 out) ----------
  f32x4 po[4] = {zero4, zero4, zero4, zero4};
  __builtin_amdgcn_s_setprio(1);
#pragma unroll
  for (int kt = 0; kt < 4; kt++) {
#pragma unroll
    for (int mt = 0; mt < 4; mt++) {
      int row = mt * 16 + l15;
      int colE = kt * 32 + g * 8;
      bf16x8 aa = *(const bf16x8*)(&smem[ATT_OFF + row * 128 + (colE ^ ((row & 7) << 3))]);
      po[mt] = __builtin_amdgcn_mfma_f32_16x16x32_bf16(aa, bwp[kt], po[mt], 0, 0, 0);
    }
  }
  __builtin_amdgcn_s_setprio(0);
  // toks for mt 0..2 are all < 48 -> unconditional; mt=3 holds toks 48..63 of
  // which only tok 48 (g==0, reg 0) is real -> single predicated store.
#pragma unroll
  for (int mt = 0; mt < 3; mt++)
#pragma unroll
    for (int r = 0; r < 4; r++) {
      int tok = mt * 16 + g * 4 + r;
      size_t off = winbase + ((size_t)(tok / 7) * 112 + (tok % 7)) * 128 + ccol;
      out[off] = po[mt][r] + biasp;
    }
  if (g == 0) {
    size_t off = winbase + ((size_t)6 * 112 + 6) * 128 + ccol;   // tok 48 = (6,6)
    out[off] = po[3][0] + biasp;
  }
}

extern "C" void kernel_launch(void* const* d_in, const int* in_sizes, int n_in,
                              void* d_out, int out_size, void* d_ws, size_t ws_size,
                              hipStream_t stream) {
  (void)in_sizes; (void)n_in; (void)out_size; (void)ws_size;
  const float* x     = (const float*)d_in[0];
  const float* wqkv  = (const float*)d_in[1];
  const float* bqkv  = (const float*)d_in[2];
  const float* wproj = (const float*)d_in[3];
  const float* bproj = (const float*)d_in[4];
  unsigned short* wt = (unsigned short*)d_ws;   // 131072 B: wqkvT + wprojT (bf16)

  hipLaunchKernelGGL(prep_weights, dim3(256), dim3(256), 0, stream, wqkv, wproj, wt);
  hipLaunchKernelGGL(win_attn, dim3(4096), dim3(TPB), 0, stream,
                     x, bqkv, bproj, wt, (float*)d_out);
}

// Round 14
// 84.991 us; speedup vs baseline: 1.3161x; 1.1245x over previous
//
#include <hip/hip_runtime.h>
#include <hip/hip_bf16.h>

typedef short bf16x8 __attribute__((ext_vector_type(8)));
typedef short bf16x4 __attribute__((ext_vector_type(4)));
typedef float f32x4 __attribute__((ext_vector_type(4)));
typedef unsigned short ushort8v __attribute__((ext_vector_type(8)));

#define TPB  512
#define NWIN 8            // windows per persistent block; grid = 4096/NWIN = 512 = 2/CU exactly

// HW bf16 convert (RNE) — compiler emits v_cvt_pk_bf16_f32; do NOT hand-roll (r7/r8 lesson).
__device__ __forceinline__ unsigned short f2bf(float f) {
  __hip_bfloat16 h = __float2bfloat16(f);
  return __builtin_bit_cast(unsigned short, h);
}

__device__ __forceinline__ bf16x4 pack4(float a, float b, float c, float d) {
  bf16x4 v;
  v[0] = (short)f2bf(a); v[1] = (short)f2bf(b);
  v[2] = (short)f2bf(c); v[3] = (short)f2bf(d);
  return v;
}

// K=16 bf16 MFMA. A-frag k-pattern (k=4g+j) == D-layout row pattern (row=4g+r),
// so D-fragments feed K=16 MFMAs directly; with B = c*Identity it TRANSPOSES a
// 16x16 block in the matrix pipe (D = c*X^T).
__device__ __forceinline__ f32x4 mfma16(bf16x4 a, bf16x4 b, f32x4 c) {
#if __has_builtin(__builtin_amdgcn_mfma_f32_16x16x16_bf16)
  return __builtin_amdgcn_mfma_f32_16x16x16_bf16(a, b, c, 0, 0, 0);
#elif __has_builtin(__builtin_amdgcn_mfma_f32_16x16x16bf16_1k)
  return __builtin_amdgcn_mfma_f32_16x16x16bf16_1k(a, b, c, 0, 0, 0);
#else
  f32x4 d;
  asm("v_mfma_f32_16x16x16_bf16 %0, %1, %2, %3" : "=v"(d) : "v"(a), "v"(b), "v"(c));
  return d;
#endif
}

// raw v_exp_f32 / v_rcp_f32 — skip ocml edge-case wrappers (r12/r13: real VALU win)
__device__ __forceinline__ float exp2_raw(float x) {
#if __has_builtin(__builtin_amdgcn_exp2f)
  return __builtin_amdgcn_exp2f(x);
#else
  float r; asm("v_exp_f32 %0, %1" : "=v"(r) : "v"(x)); return r;
#endif
}
__device__ __forceinline__ float rcp_raw(float x) {
#if __has_builtin(__builtin_amdgcn_rcpf)
  return __builtin_amdgcn_rcpf(x);
#else
  float r; asm("v_rcp_f32 %0, %1" : "=v"(r) : "v"(x)); return r;
#endif
}

// LDS map (ushort elems). Persistent-loop overlays (r14):
//   [0..8192)      sWin (staging, overlays dead Q of previous iteration)
//   [0..10240)     Q    (QKV phase -> bq regs)
//   [10240..20480) K    (QKV phase -> ak regs)
//   [10240..18432) ATT  (overlays dead K — this is what frees the stage-write slot)
//   [20480..29696) VT
#define Q_OFF   0
#define K_OFF   10240
#define ATT_OFF 10240
#define VT_OFF  20480
#define SMEM_ELEMS 29696 // 59,392 B -> 2 blocks/CU (118,784 <= 131,072 usable)

// scale * log2(e): softmax in log2 domain; logits tiny -> no max-subtraction needed.
#define CQ 0.25501817f   // (1/sqrt(32)) * 1.4426950408889634

__global__ void prep_weights(const float* __restrict__ wqkv,
                             const float* __restrict__ wproj,
                             unsigned short* __restrict__ wt) {
  int idx = blockIdx.x * 256 + threadIdx.x;
  if (idx < 384 * 128) {                 // wqkvT[n][k] = bf16(wqkv[k][n])
    int n = idx >> 7, k = idx & 127;
    wt[idx] = f2bf(wqkv[k * 384 + n]);
  } else if (idx < 384 * 128 + 128 * 128) { // wprojT[c][k] = bf16(wproj[k][c])
    int j = idx - 384 * 128;
    int c = j >> 7, k = j & 127;
    wt[idx] = f2bf(wproj[k * 128 + c]);
  }
}

__device__ __forceinline__ size_t winbase_of(int wid) {
  int b = wid >> 8, wh = (wid >> 4) & 15, ww = wid & 15;
  return (((size_t)b * 112 + wh * 7) * 112 + ww * 7) * 128;
}

__launch_bounds__(TPB, 2)   // cap 128 VGPR; residency is LDS-pinned at 2 blocks/CU anyway
__global__ void win_attn(const float* __restrict__ x,
                         const float* __restrict__ bqkv,
                         const float* __restrict__ bproj,
                         const unsigned short* __restrict__ wt,
                         float* __restrict__ out) {
  __shared__ __align__(16) unsigned short smem[SMEM_ELEMS];
  const int tid  = threadIdx.x;
  const int wave = tid >> 6;
  const int lane = tid & 63;
  const int g    = lane >> 4;   // 16-lane group id (0..3)
  const int l15  = lane & 15;

  const unsigned short* wqkvT  = wt;               // [384][128] bf16
  const unsigned short* wprojT = wt + 384 * 128;   // [128][128] bf16

  // identity B-frags for the transpose-mfma: B[k=4g+j][col=l15] = c * delta(4g+j, l15)
  bf16x4 idQ = {0, 0, 0, 0}, idK = {0, 0, 0, 0};
  if ((l15 >> 2) == g) {
    idQ[l15 & 3] = (short)f2bf(CQ);       // Q gets scale*log2e folded in
    idK[l15 & 3] = (short)0x3F80;         // 1.0 bf16
  }

  // staging geometry (invariant): thread covers rows row0 and row0+32; rows>48 clamp
  // to row 48 (finite garbage safe: K toks masked, V toks killed by P=0, Q rows unused).
  // (row+32)&7 == row&7, so both chunks share the same XOR granule.
  const int row0  = tid >> 4, c8 = tid & 15;
  const int rowc0 = min(row0, 48), rowc1 = min(row0 + 32, 48);
  const int xo0   = ((rowc0 / 7) * 112 + (rowc0 % 7)) * 128 + c8 * 8;
  const int xo1   = ((rowc1 / 7) * 112 + (rowc1 % 7)) * 128 + c8 * 8;
  const int sw    = (c8 * 8) ^ ((row0 & 7) << 3);
  const int dst0  = row0 * 128 + sw;
  const int dst1  = (row0 + 32) * 128 + sw;

  const f32x4 zero4 = {0.f, 0.f, 0.f, 0.f};
  const int h    = wave >> 1;
  const int half = wave & 1;
  const int ccol = wave * 16 + l15;

  // ---------- prologue: stage window 0 ----------
  float4 pfa, pfb, pfc, pfd;
  {
    size_t wb0 = winbase_of((int)blockIdx.x);   // w=0: wid = blockIdx.x
    const float4* s0 = (const float4*)(x + wb0 + xo0);
    const float4* s1 = (const float4*)(x + wb0 + xo1);
    pfa = s0[0]; pfb = s0[1]; pfc = s1[0]; pfd = s1[1];
  }
  {
    ushort8v v8;
    v8[0]=f2bf(pfa.x); v8[1]=f2bf(pfa.y); v8[2]=f2bf(pfa.z); v8[3]=f2bf(pfa.w);
    v8[4]=f2bf(pfb.x); v8[5]=f2bf(pfb.y); v8[6]=f2bf(pfb.z); v8[7]=f2bf(pfb.w);
    *(ushort8v*)(&smem[dst0]) = v8;
    v8[0]=f2bf(pfc.x); v8[1]=f2bf(pfc.y); v8[2]=f2bf(pfc.z); v8[3]=f2bf(pfc.w);
    v8[4]=f2bf(pfd.x); v8[5]=f2bf(pfd.y); v8[6]=f2bf(pfd.z); v8[7]=f2bf(pfd.w);
    *(ushort8v*)(&smem[dst1]) = v8;
  }
  __syncthreads();   // S0: sWin(0) visible

  for (int w = 0; w < NWIN; w++) {
    const int wid = w * 512 + (int)blockIdx.x;
    const size_t winbase = winbase_of(wid);

    // ---------- af loads (sWin -> regs) ----------
    bf16x8 af[4][4];
#pragma unroll
    for (int mt = 0; mt < 4; mt++)
#pragma unroll
      for (int kt = 0; kt < 4; kt++) {
        int row = mt * 16 + l15;
        int colE = kt * 32 + g * 8;
        af[mt][kt] = *(const bf16x8*)(&smem[row * 128 + (colE ^ ((row & 7) << 3))]);
      }
    __syncthreads();   // S1: af (and prev-iter proj ATT reads) done; QKV writes safe

    // ---------- phase 1: QKV = win @ w_qkv + b_qkv ----------
#pragma unroll
    for (int i = 0; i < 3; i++) {
      int nt = wave * 3 + i;          // 0..23 (n-tile of 384)
      int n  = nt * 16 + l15;
      float bias = bqkv[n];
      f32x4 binit = {bias, bias, bias, bias};

      bf16x8 bw[4];
#pragma unroll
      for (int kt = 0; kt < 4; kt++)
        bw[kt] = *(const bf16x8*)(wqkvT + n * 128 + kt * 32 + g * 8);

      f32x4 acc[4] = {binit, binit, binit, binit};
      __builtin_amdgcn_s_setprio(1);
#pragma unroll
      for (int kt = 0; kt < 4; kt++)
#pragma unroll
        for (int mt = 0; mt < 4; mt++)
          acc[mt] = __builtin_amdgcn_mfma_f32_16x16x32_bf16(af[mt][kt], bw[kt], acc[mt], 0, 0, 0);
      __builtin_amdgcn_s_setprio(0);

      int sec = nt >> 3;       // 0=Q 1=K 2=V (uniform per (wave,i))
      if (sec == 2) {
        int hn = n & 127, hh = hn >> 5, d = hn & 31;
#pragma unroll
        for (int mt = 0; mt < 4; mt++) {
          bf16x4 pv = pack4(acc[mt][0], acc[mt][1], acc[mt][2], acc[mt][3]);
          *(bf16x4*)(&smem[VT_OFF + hh * 2304 + d * 72 + mt * 16 + g * 4]) = pv;
        }
      } else {
        int t7 = nt & 7;
        int hh = t7 >> 1, d0 = (t7 & 1) * 16;
        const bf16x4 idf = (sec == 0) ? idQ : idK;
        const int base = (sec == 0 ? Q_OFF : K_OFF) + hh * 2560 + d0 + g * 4;
#pragma unroll
        for (int mt = 0; mt < 4; mt++) {
          bf16x4 ax = pack4(acc[mt][0], acc[mt][1], acc[mt][2], acc[mt][3]);
          f32x4 dt = mfma16(ax, idf, zero4);
          bf16x4 wv = pack4(dt[0], dt[1], dt[2], dt[3]);
          *(bf16x4*)(&smem[base + (mt * 16 + l15) * 40]) = wv;
        }
      }
    }
    __syncthreads();   // S2: Q/K/VT visible

    // ---------- phase 2: attention, swapped QK^T ----------
    bf16x8 ak[4];
#pragma unroll
    for (int kt = 0; kt < 4; kt++) {
      int row = kt * 16 + l15;
      ak[kt] = *(const bf16x8*)(&smem[K_OFF + h * 2560 + row * 40 + g * 8]);
    }
    bf16x8 bq[2];
#pragma unroll
    for (int qt = 0; qt < 2; qt++) {
      int row = half * 32 + qt * 16 + l15;
      bq[qt] = *(const bf16x8*)(&smem[Q_OFF + h * 2560 + row * 40 + g * 8]);
    }
    bf16x4 bv16[2][4];
#pragma unroll
    for (int nt2 = 0; nt2 < 2; nt2++)
#pragma unroll
      for (int kt = 0; kt < 4; kt++)
        bv16[nt2][kt] = *(const bf16x4*)(&smem[VT_OFF + h * 2304 + (nt2 * 16 + l15) * 72 + kt * 16 + g * 4]);

    f32x4 s[4][2];
    __builtin_amdgcn_s_setprio(1);
#pragma unroll
    for (int kt = 0; kt < 4; kt++)
#pragma unroll
      for (int qt = 0; qt < 2; qt++)
        s[kt][qt] = __builtin_amdgcn_mfma_f32_16x16x32_bf16(ak[kt], bq[qt], zero4, 0, 0, 0);
    __builtin_amdgcn_s_setprio(0);

    // softmax (no max-subtraction; only tok 48 of kt=3 is valid)
    bf16x4 ap16[2][4];
    const bool v48 = (g == 0);
#pragma unroll
    for (int qt = 0; qt < 2; qt++) {
      float sum = 0.f;
#pragma unroll
      for (int kt = 0; kt < 3; kt++)
#pragma unroll
        for (int r = 0; r < 4; r++) {
          float p = exp2_raw(s[kt][qt][r]);
          s[kt][qt][r] = p;
          sum += p;
        }
      float p3 = v48 ? exp2_raw(s[3][qt][0]) : 0.0f;
      sum += p3;
      sum += __shfl_xor(sum, 16);
      sum += __shfl_xor(sum, 32);
      float inv = rcp_raw(sum);
#pragma unroll
      for (int kt = 0; kt < 3; kt++)
        ap16[qt][kt] = pack4(s[kt][qt][0] * inv, s[kt][qt][1] * inv,
                             s[kt][qt][2] * inv, s[kt][qt][3] * inv);
      ap16[qt][3] = pack4(p3 * inv, 0.f, 0.f, 0.f);
    }

    // PV straight from registers
    f32x4 o[2][2] = {{zero4, zero4}, {zero4, zero4}};
    __builtin_amdgcn_s_setprio(1);
#pragma unroll
    for (int kt = 0; kt < 4; kt++)
#pragma unroll
      for (int m2 = 0; m2 < 2; m2++)
#pragma unroll
        for (int nt2 = 0; nt2 < 2; nt2++)
          o[m2][nt2] = mfma16(ap16[m2][kt], bv16[nt2][kt], o[m2][nt2]);
    __builtin_amdgcn_s_setprio(0);

    // transpose O tiles in the matrix pipe (reg-only)
    bf16x4 attw[2][2];
#pragma unroll
    for (int m2 = 0; m2 < 2; m2++)
#pragma unroll
      for (int nt2 = 0; nt2 < 2; nt2++) {
        bf16x4 ox = pack4(o[m2][nt2][0], o[m2][nt2][1], o[m2][nt2][2], o[m2][nt2][3]);
        f32x4 ot = mfma16(ox, idK, zero4);
        attw[m2][nt2] = pack4(ot[0], ot[1], ot[2], ot[3]);
      }

    // T14: issue next window's staging loads NOW (consumed after S3) — latency
    // hides under the rest of attention + barriers + ATT writes.
    if (w < NWIN - 1) {
      size_t wbn = winbase_of(wid + 512);
      const float4* s0 = (const float4*)(x + wbn + xo0);
      const float4* s1 = (const float4*)(x + wbn + xo1);
      pfa = s0[0]; pfb = s0[1]; pfc = s1[0]; pfd = s1[1];
    }

    // proj weights (L2-resident, independent of LDS)
    bf16x8 bwp[4];
#pragma unroll
    for (int kt = 0; kt < 4; kt++)
      bwp[kt] = *(const bf16x8*)(wprojT + ccol * 128 + kt * 32 + g * 8);
    float biasp = bproj[ccol];

    __syncthreads();   // S3: all Q/K/VT reads done; ATT (over K) + sWin (over Q) writable

#pragma unroll
    for (int m2 = 0; m2 < 2; m2++)
#pragma unroll
      for (int nt2 = 0; nt2 < 2; nt2++) {
        int tok  = (half * 2 + m2) * 16 + l15;
        int col0 = h * 32 + nt2 * 16 + g * 4;
        *(bf16x4*)(&smem[ATT_OFF + tok * 128 + (col0 ^ ((tok & 7) << 3))]) = attw[m2][nt2];
      }
    if (w < NWIN - 1) {
      ushort8v v8;
      v8[0]=f2bf(pfa.x); v8[1]=f2bf(pfa.y); v8[2]=f2bf(pfa.z); v8[3]=f2bf(pfa.w);
      v8[4]=f2bf(pfb.x); v8[5]=f2bf(pfb.y); v8[6]=f2bf(pfb.z); v8[7]=f2bf(pfb.w);
      *(ushort8v*)(&smem[dst0]) = v8;
      v8[0]=f2bf(pfc.x); v8[1]=f2bf(pfc.y); v8[2]=f2bf(pfc.z); v8[3]=f2bf(pfc.w);
      v8[4]=f2bf(pfd.x); v8[5]=f2bf(pfd.y); v8[6]=f2bf(pfd.z); v8[7]=f2bf(pfd.w);
      *(ushort8v*)(&smem[dst1]) = v8;
    }
    __syncthreads();   // S4: ATT + next sWin visible

    // ---------- proj + bias + store (fp32 out) ----------
    f32x4 po[4] = {zero4, zero4, zero4, zero4};
    __builtin_amdgcn_s_setprio(1);
#pragma unroll
    for (int kt = 0; kt < 4; kt++) {
#pragma unroll
      for (int mt = 0; mt < 4; mt++) {
        int row = mt * 16 + l15;
        int colE = kt * 32 + g * 8;
        bf16x8 aa = *(const bf16x8*)(&smem[ATT_OFF + row * 128 + (colE ^ ((row & 7) << 3))]);
        po[mt] = __builtin_amdgcn_mfma_f32_16x16x32_bf16(aa, bwp[kt], po[mt], 0, 0, 0);
      }
    }
    __builtin_amdgcn_s_setprio(0);
#pragma unroll
    for (int mt = 0; mt < 3; mt++)
#pragma unroll
      for (int r = 0; r < 4; r++) {
        int tok = mt * 16 + g * 4 + r;
        size_t off = winbase + ((size_t)(tok / 7) * 112 + (tok % 7)) * 128 + ccol;
        out[off] = po[mt][r] + biasp;
      }
    if (g == 0) {
      size_t off = winbase + ((size_t)6 * 112 + 6) * 128 + ccol;   // tok 48 = (6,6)
      out[off] = po[3][0] + biasp;
    }
  }
}

extern "C" void kernel_launch(void* const* d_in, const int* in_sizes, int n_in,
                              void* d_out, int out_size, void* d_ws, size_t ws_size,
                              hipStream_t stream) {
  (void)in_sizes; (void)n_in; (void)out_size; (void)ws_size;
  const float* x     = (const float*)d_in[0];
  const float* wqkv  = (const float*)d_in[1];
  const float* bqkv  = (const float*)d_in[2];
  const float* wproj = (const float*)d_in[3];
  const float* bproj = (const float*)d_in[4];
  unsigned short* wt = (unsigned short*)d_ws;   // 131072 B: wqkvT + wprojT (bf16)

  hipLaunchKernelGGL(prep_weights, dim3(256), dim3(256), 0, stream, wqkv, wproj, wt);
  hipLaunchKernelGGL(win_attn, dim3(4096 / NWIN), dim3(TPB), 0, stream,
                     x, bqkv, bproj, wt, (float*)d_out);
}